// Round 9
// baseline (199.193 us; speedup 1.0000x reference)
//
#include <hip/hip_runtime.h>

// MiniSTU: out[b,l,o] = sum_k sum_{s<=l} phi[l-s,k]*(x@Mp[k])[o] + (-1)^(l-s)-weighted Mm term
// Stage 1: Z[b][kk][o][s]  (s pre-swizzled), gl16 counted-vmcnt MFMA GEMM
// Stage 2: 128l x 128o tiles. A(Toeplitz, L2-hot) -> registers (1-ahead dbuf);
//          Z -> 4-buf LDS via gl16, 2-ahead, counted vmcnt. XCD-chunked remap.

#define ZB_ 12582912  // Z elems per batch (48*256*1024)

typedef __attribute__((ext_vector_type(8))) short bf16x8;
typedef __attribute__((ext_vector_type(4))) float f32x4;

__device__ inline unsigned short f2bf(float f) {
    unsigned u = __float_as_uint(f);
    u += 0x7FFFu + ((u >> 16) & 1u);   // RNE
    return (unsigned short)(u >> 16);
}

__device__ inline void gl16(const unsigned short* g, unsigned short* l) {
    __builtin_amdgcn_global_load_lds((const __attribute__((address_space(1))) void*)g,
                                     (__attribute__((address_space(3))) void*)l, 16, 0, 0);
}

// ---- merged prep: [0,1024) prep_x | [1024,1792) prep_toep | [1792,4864) transpose_M
__global__ __launch_bounds__(256) void k_prep_all(const float* __restrict__ x,
                                                  const float* __restrict__ phi,
                                                  const float* __restrict__ Mp,
                                                  const float* __restrict__ Mm,
                                                  unsigned short* __restrict__ xb,
                                                  unsigned short* __restrict__ ToepA,
                                                  unsigned short* __restrict__ MbT) {
    __shared__ float tile[32][33];
    int bid = blockIdx.x, tid = threadIdx.x;
    if (bid < 1024) {
        // x (f32) -> xb (bf16), i pre-swizzled within 64-chunks by (s&7)<<3
        int i = (bid * 256 + tid) * 4;
        float4 v = *(const float4*)(x + i);
        ushort4 o;
        o.x = f2bf(v.x); o.y = f2bf(v.y); o.z = f2bf(v.z); o.w = f2bf(v.w);
        int row = i >> 8, col = i & 255;
        int dst = (row << 8) | (col & 192) | ((col & 63) ^ ((row & 7) << 3));
        *(ushort4*)(xb + dst) = o;
    } else if (bid < 1792) {
        // ToepA[kk][didx][i][j] = sgn*phi[(didx-1)*64+i-j][k]  (LINEAR, reg-loaded)
        int r = bid - 1024;
        int kk = r >> 4;
        int dm = (r & 15) - 1;
        int k = (kk < 24) ? kk : kk - 24;
        int i = tid >> 1, j0 = (tid & 1) * 32;
        unsigned short* dst = ToepA + ((size_t)kk * 16 + (dm + 1)) * 8192 + i * 64;
#pragma unroll
        for (int q = 0; q < 8; ++q) {
            int j = j0 + q * 4;
            unsigned short e[4];
#pragma unroll
            for (int ee = 0; ee < 4; ++ee) {
                int t = dm * 64 + i - (j + ee);
                float v = 0.f;
                if (t >= 0 && t < 1024) {
                    v = phi[t * 24 + k];
                    if (kk >= 24 && (t & 1)) v = -v;
                }
                e[ee] = f2bf(v);
            }
            ushort4 ov; ov.x = e[0]; ov.y = e[1]; ov.z = e[2]; ov.w = e[3];
            *(ushort4*)(dst + j) = ov;
        }
    } else {
        // MbT[kk][o][i'] = M(kk)[i][o], i pre-swizzled by (o&7)<<3
        int flat = bid - 1792;
        int kk = flat >> 6, rr = flat & 63;
        int i0 = (rr >> 3) * 32, o0 = (rr & 7) * 32;
        int tx = tid & 31, ty = tid >> 5;
        const float* src = ((kk < 24) ? Mp : Mm) + (size_t)((kk < 24) ? kk : kk - 24) * 65536;
        for (int j = 0; j < 4; ++j)
            tile[ty + j * 8][tx] = src[(i0 + ty + j * 8) * 256 + o0 + tx];
        __syncthreads();
        for (int j = 0; j < 4; ++j) {
            int orow = o0 + ty + j * 8, i = i0 + tx;
            int ic = (i & 192) | ((i & 63) ^ ((orow & 7) << 3));
            MbT[(size_t)kk * 65536 + orow * 256 + ic] = f2bf(tile[tx][ty + j * 8]);
        }
    }
}

// ---- stage 1: grid (8 m-tiles, 96 = 48kk x 2 o-halves, g batches), 256 thr ---
// Counted-vmcnt pipeline: A(xb) 2-buf 1-ahead, B(MbT) 3-buf 2-ahead. 4 K-chunks.
__global__ __launch_bounds__(256, 2) void k_stage1(const unsigned short* __restrict__ xb0,
                                                   const unsigned short* __restrict__ MbT,
                                                   unsigned short* __restrict__ Z) {
    __shared__ unsigned short Ab[2][8192];
    __shared__ unsigned short Bb[3][8192];
    int tid = threadIdx.x, lane = tid & 63, w = tid >> 6;
    int wm = w >> 1, wn = w & 1;
    int m0 = blockIdx.x * 128;
    int kk = blockIdx.y >> 1;
    int o0 = (blockIdx.y & 1) * 128;
    int b  = blockIdx.z;
    const unsigned short* xb_b = xb0 + (size_t)b * 262144;
    unsigned short* Zb = Z + (size_t)b * ZB_;
    const unsigned short* Bsrc = MbT + (size_t)kk * 65536;
    int l16 = lane & 15, kofs = (lane >> 4) * 8;
    int sw = (l16 & 7) << 3;
    int r8 = lane >> 3, cg = lane & 7;

    int arow[4], brow[4], lofs[4];
#pragma unroll
    for (int q = 0; q < 4; ++q) {
        int rr = q * 32 + w * 8 + r8;
        arow[q] = (m0 + rr) * 256 + cg * 8;
        brow[q] = (o0 + rr) * 256 + cg * 8;
        lofs[q] = q * 2048 + w * 512;
    }

    f32x4 acc[4][4];
    for (int i = 0; i < 4; ++i)
        for (int j = 0; j < 4; ++j) {
            acc[i][j][0] = 0.f; acc[i][j][1] = 0.f; acc[i][j][2] = 0.f; acc[i][j][3] = 0.f;
        }

    auto stageA = [&](int bi, int ko) {
#pragma unroll
        for (int q = 0; q < 4; ++q) gl16(xb_b + arow[q] + ko * 64, &Ab[bi][0] + lofs[q]);
    };
    auto stageB = [&](int bi, int ko) {
#pragma unroll
        for (int q = 0; q < 4; ++q) gl16(Bsrc + brow[q] + ko * 64, &Bb[bi][0] + lofs[q]);
    };

    stageA(0, 0); stageB(0, 0); stageB(1, 1);

    for (int ko = 0; ko < 4; ++ko) {
        if (ko < 3) { asm volatile("s_waitcnt vmcnt(4)" ::: "memory"); }
        else        { asm volatile("s_waitcnt vmcnt(0)" ::: "memory"); }
        __builtin_amdgcn_sched_barrier(0);
        __builtin_amdgcn_s_barrier();
        __builtin_amdgcn_sched_barrier(0);
        if (ko < 3) stageA((ko + 1) & 1, ko + 1);
        if (ko < 2) stageB((ko + 2) % 3, ko + 2);

        const unsigned short* Abase = &Ab[ko & 1][0];
        const unsigned short* Bbase = &Bb[ko % 3][0];
        __builtin_amdgcn_s_setprio(1);
#pragma unroll
        for (int ks = 0; ks < 2; ++ks) {
            int koX = (ks * 32 + kofs) ^ sw;
            bf16x8 af[4], bfv[4];
#pragma unroll
            for (int mi = 0; mi < 4; ++mi)
                af[mi] = *(const bf16x8*)(Abase + (wm * 64 + mi * 16 + l16) * 64 + koX);
#pragma unroll
            for (int ni = 0; ni < 4; ++ni)
                bfv[ni] = *(const bf16x8*)(Bbase + (wn * 64 + ni * 16 + l16) * 64 + koX);
#pragma unroll
            for (int mi = 0; mi < 4; ++mi)
#pragma unroll
                for (int ni = 0; ni < 4; ++ni)
                    acc[mi][ni] = __builtin_amdgcn_mfma_f32_16x16x32_bf16(af[mi], bfv[ni], acc[mi][ni], 0, 0, 0);
        }
        __builtin_amdgcn_s_setprio(0);
    }

    int r4 = (lane >> 4) * 4;
    for (int mi = 0; mi < 4; ++mi) {
        int sbase = m0 + wm * 64 + mi * 16 + r4;
        for (int ni = 0; ni < 4; ++ni) {
            int o = o0 + wn * 64 + ni * 16 + l16;
            ushort4 pk;
            pk.x = f2bf(acc[mi][ni][0]); pk.y = f2bf(acc[mi][ni][1]);
            pk.z = f2bf(acc[mi][ni][2]); pk.w = f2bf(acc[mi][ni][3]);
            *(ushort4*)(Zb + (size_t)kk * 262144 + (size_t)o * 1024 + (sbase ^ ((o & 7) << 3))) = pk;
        }
    }
}

// ---- stage 2: grid (4 diag-pairs, 2 o-tiles x g batches, kg), 256 thr --------
// A fragments: global->reg double-buffer (static index, unroll-by-2), 1-ahead.
// Z: gl16 -> 4 LDS buffers, 2-ahead. Steady vmcnt(24); tail vmcnt(20)/vmcnt(8).
__global__ __launch_bounds__(256, 2) void k_stage2(const unsigned short* __restrict__ Z,
                                                   const unsigned short* __restrict__ ToepA,
                                                   float* __restrict__ partial, int kkpg) {
    __shared__ unsigned short Zl[4][8192];   // 64 KB
    int tid = threadIdx.x, lane = tid & 63, w = tid >> 6;
    int wm = w >> 1, wn = w & 1;

    // XCD-chunked bijective remap (nwg % 8 == 0 always here)
    int gy = gridDim.y, nwg = 4 * gy * gridDim.z;
    int orig = blockIdx.x + blockIdx.y * 4 + blockIdx.z * 4 * gy;
    int wg = (orig & 7) * (nwg >> 3) + (orig >> 3);
    int pr = wg & 3;
    int yy = (wg >> 2) % gy;
    int zz = (wg >> 2) / gy;
    int o0 = (yy & 1) * 128;
    int b  = yy >> 1;
    int kgi = zz;
    int kk0 = kgi * kkpg;

    int l16 = lane & 15, kofs = (lane >> 4) * 8;
    int sw = (l16 & 7) << 3;
    int r8 = lane >> 3, cg = lane & 7;

    const unsigned short* Zb = Z + (size_t)b * ZB_;
    float* pb = partial + ((size_t)b * gridDim.z + kgi) * 262144;

    int zrow[4], lofs[4];
#pragma unroll
    for (int q = 0; q < 4; ++q) {
        int rr = q * 32 + w * 8 + r8;
        zrow[q] = (o0 + rr) * 1024 + cg * 8;
        lofs[q] = q * 2048 + w * 512;
    }
    int aofs[4][2];
#pragma unroll
    for (int mi = 0; mi < 4; ++mi)
#pragma unroll
        for (int ks = 0; ks < 2; ++ks)
            aofs[mi][ks] = (wm * 64 + mi * 16 + l16) * 64 + ks * 32 + kofs;

    for (int half = 0; half < 2; ++half) {
        int lb = half ? (7 - pr) : pr;
        int l0 = lb * 128;
        int nch = 2 * lb + 2;
        int total = kkpg * nch;   // always even, >= 4

        f32x4 acc[4][4];
        for (int i = 0; i < 4; ++i)
            for (int j = 0; j < 4; ++j) {
                acc[i][j][0] = 0.f; acc[i][j][1] = 0.f; acc[i][j][2] = 0.f; acc[i][j][3] = 0.f;
            }

        __syncthreads();   // previous-half LDS readers done

        auto zstage = [&](int bufi, int kkx, int sc) {
            const unsigned short* gZ = Zb + (size_t)(kk0 + kkx) * 262144 + sc * 64;
#pragma unroll
            for (int q = 0; q < 4; ++q) gl16(gZ + zrow[q], &Zl[bufi][0] + lofs[q]);
        };
        auto aload = [&](bf16x8 (&dst)[4][2], int kkx, int sc) {
            const unsigned short* gA = ToepA + ((size_t)(kk0 + kkx) * 16 + (2 * lb - sc + 1)) * 8192;
#pragma unroll
            for (int mi = 0; mi < 4; ++mi)
#pragma unroll
                for (int ks = 0; ks < 2; ++ks)
                    dst[mi][ks] = *(const bf16x8*)(gA + aofs[mi][ks]);
        };
        auto compute = [&](bf16x8 (&afr)[4][2], int bufi) {
            const unsigned short* Zbase = &Zl[bufi][0];
            __builtin_amdgcn_s_setprio(1);
#pragma unroll
            for (int ks = 0; ks < 2; ++ks) {
                int koX = (ks * 32 + kofs) ^ sw;
                bf16x8 bfv[4];
#pragma unroll
                for (int ni = 0; ni < 4; ++ni)
                    bfv[ni] = *(const bf16x8*)(Zbase + (wn * 64 + ni * 16 + l16) * 64 + koX);
#pragma unroll
                for (int mi = 0; mi < 4; ++mi)
#pragma unroll
                    for (int ni = 0; ni < 4; ++ni)
                        acc[mi][ni] = __builtin_amdgcn_mfma_f32_16x16x32_bf16(afr[mi][ks], bfv[ni], acc[mi][ni], 0, 0, 0);
            }
            __builtin_amdgcn_s_setprio(0);
        };

        bf16x8 aR[4][2], aS[4][2];

        // prologue (issue order matters for counting): Z(0), A(0)->aR, Z(1)
        zstage(0, 0, 0);
        aload(aR, 0, 0);
        zstage(1, 0, 1);

        // rolling coords: A-next = chunk 1, Z-next = chunk 2
        int scA = 1, kkA = 0;
        int scZ = 2, kkZ = 0;
        if (scZ == nch) { scZ = 0; kkZ = 1; }

        for (int j = 0; j < total - 2; j += 2) {
            // even slot j: uses aR, loads aS
            aload(aS, kkA, scA);
            ++scA; if (scA == nch) { scA = 0; ++kkA; }
            zstage((j + 2) & 3, kkZ, scZ);
            ++scZ; if (scZ == nch) { scZ = 0; ++kkZ; }
            asm volatile("s_waitcnt vmcnt(24)" ::: "memory");
            __builtin_amdgcn_sched_barrier(0);
            __builtin_amdgcn_s_barrier();
            __builtin_amdgcn_sched_barrier(0);
            compute(aR, j & 3);

            // odd slot j+1: uses aS, loads aR
            aload(aR, kkA, scA);
            ++scA; if (scA == nch) { scA = 0; ++kkA; }
            zstage((j + 3) & 3, kkZ, scZ);
            ++scZ; if (scZ == nch) { scZ = 0; ++kkZ; }
            asm volatile("s_waitcnt vmcnt(24)" ::: "memory");
            __builtin_amdgcn_sched_barrier(0);
            __builtin_amdgcn_s_barrier();
            __builtin_amdgcn_sched_barrier(0);
            compute(aS, (j + 1) & 3);
        }

        // peeled slot total-2 (even: uses aR, loads aS=A(total-1), no Z)
        aload(aS, kkA, scA);
        asm volatile("s_waitcnt vmcnt(20)" ::: "memory");
        __builtin_amdgcn_sched_barrier(0);
        __builtin_amdgcn_s_barrier();
        __builtin_amdgcn_sched_barrier(0);
        compute(aR, (total - 2) & 3);

        // peeled slot total-1 (odd: uses aS, no loads)
        asm volatile("s_waitcnt vmcnt(8)" ::: "memory");
        __builtin_amdgcn_sched_barrier(0);
        __builtin_amdgcn_s_barrier();
        __builtin_amdgcn_sched_barrier(0);
        compute(aS, (total - 1) & 3);

        int r4 = (lane >> 4) * 4;
        for (int mi = 0; mi < 4; ++mi) {
            int l = l0 + wm * 64 + mi * 16 + r4;
            for (int ni = 0; ni < 4; ++ni) {
                int o = o0 + wn * 64 + ni * 16 + l16;
                float* dst = pb + (size_t)l * 256 + o;
                dst[0]   = acc[mi][ni][0];
                dst[256] = acc[mi][ni][1];
                dst[512] = acc[mi][ni][2];
                dst[768] = acc[mi][ni][3];
            }
        }
    }
}

// ---- reduce: out[b][l][o] = sum_kg partial[b][kg][l][o] ----------------------
__global__ void k_reduce(const float* __restrict__ partial, float* __restrict__ outg, int kg) {
    const float* pb = partial + (size_t)blockIdx.y * kg * 262144;
    int i = (blockIdx.x * 256 + threadIdx.x) * 4;
    float4 s = *(const float4*)(pb + i);
    for (int kgi = 1; kgi < kg; ++kgi) {
        float4 v = *(const float4*)(pb + (size_t)kgi * 262144 + i);
        s.x += v.x; s.y += v.y; s.z += v.z; s.w += v.w;
    }
    *(float4*)(outg + (size_t)blockIdx.y * 262144 + i) = s;
}

extern "C" void kernel_launch(void* const* d_in, const int* in_sizes, int n_in,
                              void* d_out, int out_size, void* d_ws, size_t ws_size,
                              hipStream_t stream) {
    const float* x   = (const float*)d_in[0];   // [4,1024,256]
    const float* phi = (const float*)d_in[1];   // [1024,24]
    const float* Mp  = (const float*)d_in[2];   // [24,256,256]
    const float* Mm  = (const float*)d_in[3];   // [24,256,256]
    float* out = (float*)d_out;                 // [4,1024,256]

    char* ws = (char*)d_ws;
    unsigned short* xb    = (unsigned short*)(ws);             //  2,097,152 B
    unsigned short* MbT   = (unsigned short*)(ws + 2097152);   //  6,291,456 B
    unsigned short* ToepA = (unsigned short*)(ws + 8388608);   // 12,582,912 B
    unsigned short* Zbuf  = (unsigned short*)(ws + 20971520);  // g * 25,165,824 B
    const size_t fixed = 20971520;

    int g = 4, kg = 16;
    auto need = [&](int gg, int kk) {
        return fixed + (size_t)gg * 25165824 + (size_t)gg * (size_t)kk * 1048576;
    };
    if (need(4, 16) > ws_size) {
        kg = 12;
        if (need(4, 12) > ws_size) {
            g = 2; kg = 16;
            if (need(2, 16) > ws_size) {
                kg = 12;
                if (need(2, 12) > ws_size) {
                    g = 1; kg = 16;
                    if (need(1, 16) > ws_size) {
                        kg = 12;
                        if (need(1, 12) > ws_size) kg = 6;
                    }
                }
            }
        }
    }
    float* partial = (float*)(ws + fixed + (size_t)g * 25165824);

    k_prep_all<<<dim3(4864), dim3(256), 0, stream>>>(x, phi, Mp, Mm, xb, ToepA, MbT);

    for (int b0 = 0; b0 < 4; b0 += g) {
        k_stage1<<<dim3(8, 96, g), dim3(256), 0, stream>>>(xb + (size_t)b0 * 262144, MbT, Zbuf);
        k_stage2<<<dim3(4, 2 * g, kg), dim3(256), 0, stream>>>(Zbuf, ToepA, partial, 48 / kg);
        k_reduce<<<dim3(256, g), dim3(256), 0, stream>>>(partial, out + (size_t)b0 * 262144, kg);
    }
}

// Round 10
// 129.888 us; speedup vs baseline: 1.5336x; 1.5336x over previous
//
#include <hip/hip_runtime.h>

// MiniSTU: out[b,l,o] = sum_k sum_{s<=l} phi[l-s,k]*(x@Mp[k])[o] + (-1)^(l-s)-weighted Mm term
// Stage 1: Z[b][kk][o][s] gl16 counted-vmcnt GEMM, 32-K chunks, 40KB LDS (4 blocks/CU),
//          XCD-chunked remap. xb/MbT pre-swizzled within 32-col chunks.
// Stage 2: 128l x 128o Toeplitz GEMM, gl16 counted-vmcnt (A 1-ahead LDS, Z 2-ahead LDS),
//          XCD-chunked remap, 64-col swizzle pair (ToepA/Z). bf16 partial.

#define ZB_ 12582912  // Z elems per batch (48*256*1024)

typedef __attribute__((ext_vector_type(8))) short bf16x8;
typedef __attribute__((ext_vector_type(4))) float f32x4;

__device__ inline unsigned short f2bf(float f) {
    unsigned u = __float_as_uint(f);
    u += 0x7FFFu + ((u >> 16) & 1u);   // RNE
    return (unsigned short)(u >> 16);
}

__device__ inline float bf2f(unsigned short s) {
    unsigned u = ((unsigned)s) << 16;
    return __uint_as_float(u);
}

__device__ inline void gl16(const unsigned short* g, unsigned short* l) {
    __builtin_amdgcn_global_load_lds((const __attribute__((address_space(1))) void*)g,
                                     (__attribute__((address_space(3))) void*)l, 16, 0, 0);
}

// ---- merged prep: [0,1024) prep_x | [1024,1792) prep_toep | [1792,4864) transpose_M
__global__ __launch_bounds__(256) void k_prep_all(const float* __restrict__ x,
                                                  const float* __restrict__ phi,
                                                  const float* __restrict__ Mp,
                                                  const float* __restrict__ Mm,
                                                  unsigned short* __restrict__ xb,
                                                  unsigned short* __restrict__ ToepA,
                                                  unsigned short* __restrict__ MbT) {
    __shared__ float tile[32][33];
    int bid = blockIdx.x, tid = threadIdx.x;
    if (bid < 1024) {
        // x (f32) -> xb (bf16), i pre-swizzled within 32-chunks by ((s>>1)&3)<<3
        int i = (bid * 256 + tid) * 4;
        float4 v = *(const float4*)(x + i);
        ushort4 o;
        o.x = f2bf(v.x); o.y = f2bf(v.y); o.z = f2bf(v.z); o.w = f2bf(v.w);
        int row = i >> 8, col = i & 255;
        int dst = (row << 8) | (col & 224) | ((col & 31) ^ (((row >> 1) & 3) << 3));
        *(ushort4*)(xb + dst) = o;
    } else if (bid < 1792) {
        // ToepA[kk][didx][i][j'] = sgn*phi[(didx-1)*64+i-j][k], j' = j ^ ((i&7)<<3)
        int r = bid - 1024;
        int kk = r >> 4;
        int dm = (r & 15) - 1;
        int k = (kk < 24) ? kk : kk - 24;
        int i = tid >> 1, j0 = (tid & 1) * 32;
        unsigned short* dst = ToepA + ((size_t)kk * 16 + (dm + 1)) * 8192 + i * 64;
        int sw = (i & 7) << 3;
#pragma unroll
        for (int q = 0; q < 8; ++q) {
            int j = j0 + q * 4;
            unsigned short e[4];
#pragma unroll
            for (int ee = 0; ee < 4; ++ee) {
                int t = dm * 64 + i - (j + ee);
                float v = 0.f;
                if (t >= 0 && t < 1024) {
                    v = phi[t * 24 + k];
                    if (kk >= 24 && (t & 1)) v = -v;
                }
                e[ee] = f2bf(v);
            }
            ushort4 ov; ov.x = e[0]; ov.y = e[1]; ov.z = e[2]; ov.w = e[3];
            *(ushort4*)(dst + (j ^ sw)) = ov;
        }
    } else {
        // MbT[kk][o][i'] = M(kk)[i][o], i pre-swizzled within 32 by ((o>>1)&3)<<3
        int flat = bid - 1792;
        int kk = flat >> 6, rr = flat & 63;
        int i0 = (rr >> 3) * 32, o0 = (rr & 7) * 32;
        int tx = tid & 31, ty = tid >> 5;
        const float* src = ((kk < 24) ? Mp : Mm) + (size_t)((kk < 24) ? kk : kk - 24) * 65536;
        for (int j = 0; j < 4; ++j)
            tile[ty + j * 8][tx] = src[(i0 + ty + j * 8) * 256 + o0 + tx];
        __syncthreads();
        for (int j = 0; j < 4; ++j) {
            int orow = o0 + ty + j * 8, i = i0 + tx;
            int ic = (i & 224) | ((i & 31) ^ (((orow >> 1) & 3) << 3));
            MbT[(size_t)kk * 65536 + orow * 256 + ic] = f2bf(tile[tx][ty + j * 8]);
        }
    }
}

// ---- stage 1: work (8 m-tiles, 96 = 48kk x 2 o-halves, g batches), 256 thr ---
// 32-K chunks x8, Ab 2-buf 1-ahead + Bb 3-buf 2-ahead (40KB), 4 blocks/CU.
__global__ __launch_bounds__(256, 4) void k_stage1(const unsigned short* __restrict__ xb0,
                                                   const unsigned short* __restrict__ MbT,
                                                   unsigned short* __restrict__ Z) {
    __shared__ unsigned short Ab[2][4096];
    __shared__ unsigned short Bb[3][4096];
    int tid = threadIdx.x, lane = tid & 63, w = tid >> 6;
    int wm = w >> 1, wn = w & 1;

    // XCD-chunked bijective remap: consecutive work ids co-locate on an XCD.
    int nwg = 768 * gridDim.z;
    int orig = blockIdx.x + blockIdx.y * 8 + blockIdx.z * 768;
    int wg = (orig & 7) * (nwg >> 3) + (orig >> 3);
    int m0 = (wg & 7) * 128;
    int rem = wg >> 3;
    int yy = rem % 96;
    int b  = rem / 96;
    int kk = yy >> 1;
    int o0 = (yy & 1) * 128;

    const unsigned short* xb_b = xb0 + (size_t)b * 262144;
    unsigned short* Zb = Z + (size_t)b * ZB_;
    const unsigned short* Bsrc = MbT + (size_t)kk * 65536;
    int l16 = lane & 15, kofs = (lane >> 4) * 8;
    int sw32 = ((l16 >> 1) & 3) << 3;
    int r4l = lane >> 2, c4 = (lane & 3) * 8;

    int arow[2], brow[2], lofs[2];
#pragma unroll
    for (int q = 0; q < 2; ++q) {
        int rr = q * 64 + w * 16 + r4l;
        arow[q] = (m0 + rr) * 256 + c4;
        brow[q] = (o0 + rr) * 256 + c4;
        lofs[q] = q * 2048 + w * 512;
    }

    f32x4 acc[4][4];
    for (int i = 0; i < 4; ++i)
        for (int j = 0; j < 4; ++j) {
            acc[i][j][0] = 0.f; acc[i][j][1] = 0.f; acc[i][j][2] = 0.f; acc[i][j][3] = 0.f;
        }

    auto stageA = [&](int bi, int ko) {
#pragma unroll
        for (int q = 0; q < 2; ++q) gl16(xb_b + arow[q] + ko * 32, &Ab[bi][0] + lofs[q]);
    };
    auto stageB = [&](int bi, int ko) {
#pragma unroll
        for (int q = 0; q < 2; ++q) gl16(Bsrc + brow[q] + ko * 32, &Bb[bi][0] + lofs[q]);
    };

    stageA(0, 0); stageB(0, 0); stageB(1, 1);   // 6 loads in flight

    for (int ko = 0; ko < 8; ++ko) {
        if (ko < 7) { asm volatile("s_waitcnt vmcnt(2)" ::: "memory"); }
        else        { asm volatile("s_waitcnt vmcnt(0)" ::: "memory"); }
        __builtin_amdgcn_sched_barrier(0);
        __builtin_amdgcn_s_barrier();
        __builtin_amdgcn_sched_barrier(0);
        if (ko < 7) stageA((ko + 1) & 1, ko + 1);
        if (ko < 6) stageB((ko + 2) % 3, ko + 2);

        const unsigned short* Abase = &Ab[ko & 1][0];
        const unsigned short* Bbase = &Bb[ko % 3][0];
        int koX = kofs ^ sw32;
        bf16x8 af[4], bfv[4];
#pragma unroll
        for (int mi = 0; mi < 4; ++mi)
            af[mi] = *(const bf16x8*)(Abase + (wm * 64 + mi * 16 + l16) * 32 + koX);
#pragma unroll
        for (int ni = 0; ni < 4; ++ni)
            bfv[ni] = *(const bf16x8*)(Bbase + (wn * 64 + ni * 16 + l16) * 32 + koX);
        __builtin_amdgcn_s_setprio(1);
#pragma unroll
        for (int mi = 0; mi < 4; ++mi)
#pragma unroll
            for (int ni = 0; ni < 4; ++ni)
                acc[mi][ni] = __builtin_amdgcn_mfma_f32_16x16x32_bf16(af[mi], bfv[ni], acc[mi][ni], 0, 0, 0);
        __builtin_amdgcn_s_setprio(0);
    }

    // store Z with s pre-swizzled by (o&7)<<3 within 64-chunks (stage2's pair)
    int r4 = (lane >> 4) * 4;
    for (int mi = 0; mi < 4; ++mi) {
        int sbase = m0 + wm * 64 + mi * 16 + r4;
        for (int ni = 0; ni < 4; ++ni) {
            int o = o0 + wn * 64 + ni * 16 + l16;
            ushort4 pk;
            pk.x = f2bf(acc[mi][ni][0]); pk.y = f2bf(acc[mi][ni][1]);
            pk.z = f2bf(acc[mi][ni][2]); pk.w = f2bf(acc[mi][ni][3]);
            *(ushort4*)(Zb + (size_t)kk * 262144 + (size_t)o * 1024 + (sbase ^ ((o & 7) << 3))) = pk;
        }
    }
}

// ---- stage 2: grid (4 diag-pairs, 2 o-tiles x g batches, kg), 256 thr --------
// Counted-vmcnt pipeline: A 1-ahead (2 bufs), Z 2-ahead (3 bufs). LDS 80 KB.
__global__ __launch_bounds__(256, 2) void k_stage2(const unsigned short* __restrict__ Z,
                                                   const unsigned short* __restrict__ ToepA,
                                                   unsigned short* __restrict__ partial, int kkpg) {
    __shared__ unsigned short Abuf[2][8192];
    __shared__ unsigned short Zbuf[3][8192];
    int tid = threadIdx.x, lane = tid & 63, w = tid >> 6;
    int wm = w >> 1, wn = w & 1;

    // XCD-chunked bijective remap (nwg % 8 == 0 always here)
    int gy = gridDim.y, nwg = 4 * gy * gridDim.z;
    int orig = blockIdx.x + blockIdx.y * 4 + blockIdx.z * 4 * gy;
    int wg = (orig & 7) * (nwg >> 3) + (orig >> 3);
    int pr = wg & 3;
    int yy = (wg >> 2) % gy;
    int zz = (wg >> 2) / gy;
    int o0 = (yy & 1) * 128;
    int b  = yy >> 1;
    int kgi = zz;
    int kk0 = kgi * kkpg;

    int l16 = lane & 15, kofs = (lane >> 4) * 8;
    int sw = (l16 & 7) << 3;
    int r8 = lane >> 3, cg = lane & 7;

    const unsigned short* Zb = Z + (size_t)b * ZB_;
    unsigned short* pb = partial + ((size_t)b * gridDim.z + kgi) * 262144;

    int arow[4], zrow[4], lofs[4];
#pragma unroll
    for (int q = 0; q < 4; ++q) {
        int rr = q * 32 + w * 8 + r8;
        arow[q] = rr * 64 + cg * 8;
        zrow[q] = (o0 + rr) * 1024 + cg * 8;
        lofs[q] = q * 2048 + w * 512;
    }

    for (int half = 0; half < 2; ++half) {
        int lb = half ? (7 - pr) : pr;
        int l0 = lb * 128;
        int nch = 2 * lb + 2;
        int total = kkpg * nch;

        f32x4 acc[4][4];
        for (int i = 0; i < 4; ++i)
            for (int j = 0; j < 4; ++j) {
                acc[i][j][0] = 0.f; acc[i][j][1] = 0.f; acc[i][j][2] = 0.f; acc[i][j][3] = 0.f;
            }

        __syncthreads();   // previous-half readers done before restaging LDS

        auto stageA = [&](int bi, int kka, int didx) {
            const unsigned short* gA = ToepA + ((size_t)kka * 16 + didx) * 8192;
#pragma unroll
            for (int q = 0; q < 4; ++q) gl16(gA + arow[q], &Abuf[bi][0] + lofs[q]);
        };
        auto stageZ = [&](int bi, int kka, int s0) {
            const unsigned short* gZ = Zb + (size_t)kka * 262144 + s0;
#pragma unroll
            for (int q = 0; q < 4; ++q) gl16(gZ + zrow[q], &Zbuf[bi][0] + lofs[q]);
        };
        auto compute = [&](int ba, int bz) {
            const unsigned short* Abase = &Abuf[ba][0];
            const unsigned short* Zbase = &Zbuf[bz][0];
            __builtin_amdgcn_s_setprio(1);
#pragma unroll
            for (int ks = 0; ks < 2; ++ks) {
                int koX = (ks * 32 + kofs) ^ sw;
                bf16x8 af[4], bfv[4];
#pragma unroll
                for (int mi = 0; mi < 4; ++mi)
                    af[mi] = *(const bf16x8*)(Abase + (wm * 64 + mi * 16 + l16) * 64 + koX);
#pragma unroll
                for (int ni = 0; ni < 4; ++ni)
                    bfv[ni] = *(const bf16x8*)(Zbase + (wn * 64 + ni * 16 + l16) * 64 + koX);
#pragma unroll
                for (int mi = 0; mi < 4; ++mi)
#pragma unroll
                    for (int ni = 0; ni < 4; ++ni)
                        acc[mi][ni] = __builtin_amdgcn_mfma_f32_16x16x32_bf16(af[mi], bfv[ni], acc[mi][ni], 0, 0, 0);
            }
            __builtin_amdgcn_s_setprio(0);
        };

        // prologue: A(0), Z(0), Z(1)
        stageA(0, kk0, 2 * lb + 1);
        stageZ(0, kk0, 0);
        stageZ(1, kk0, 64);

        int scA = 1, kkA = 0;
        int scZ = 2, kkZ = 0;
        if (scZ == nch) { scZ = 0; kkZ = 1; }
        int jz = 2;

        for (int j = 0; j < total - 1; ++j) {
            asm volatile("s_waitcnt vmcnt(4)" ::: "memory");
            __builtin_amdgcn_sched_barrier(0);
            __builtin_amdgcn_s_barrier();
            __builtin_amdgcn_sched_barrier(0);
            stageA((j + 1) & 1, kk0 + kkA, 2 * lb - scA + 1);
            ++scA; if (scA == nch) { scA = 0; ++kkA; }
            if (jz < total) {
                stageZ(jz % 3, kk0 + kkZ, scZ * 64);
                ++scZ; if (scZ == nch) { scZ = 0; ++kkZ; }
                ++jz;
            }
            compute(j & 1, j % 3);
        }
        asm volatile("s_waitcnt vmcnt(0)" ::: "memory");
        __builtin_amdgcn_sched_barrier(0);
        __builtin_amdgcn_s_barrier();
        __builtin_amdgcn_sched_barrier(0);
        compute((total - 1) & 1, (total - 1) % 3);

        int r4 = (lane >> 4) * 4;
        for (int mi = 0; mi < 4; ++mi) {
            int l = l0 + wm * 64 + mi * 16 + r4;
            for (int ni = 0; ni < 4; ++ni) {
                int o = o0 + wn * 64 + ni * 16 + l16;
                unsigned short* dst = pb + (size_t)l * 256 + o;
                dst[0]   = f2bf(acc[mi][ni][0]);
                dst[256] = f2bf(acc[mi][ni][1]);
                dst[512] = f2bf(acc[mi][ni][2]);
                dst[768] = f2bf(acc[mi][ni][3]);
            }
        }
    }
}

// ---- reduce: out[b][l][o] = sum_kg partial[b][kg][l][o] (bf16 -> f32) --------
__global__ void k_reduce(const unsigned short* __restrict__ partial, float* __restrict__ outg, int kg) {
    const unsigned short* pb = partial + (size_t)blockIdx.y * kg * 262144;
    int i = (blockIdx.x * 256 + threadIdx.x) * 8;
    float s[8];
#pragma unroll
    for (int j = 0; j < 8; ++j) s[j] = 0.f;
    for (int kgi = 0; kgi < kg; ++kgi) {
        uint4 v = *(const uint4*)(pb + (size_t)kgi * 262144 + i);
        unsigned vv[4] = {v.x, v.y, v.z, v.w};
#pragma unroll
        for (int q = 0; q < 4; ++q) {
            s[q * 2]     += bf2f((unsigned short)(vv[q] & 0xFFFF));
            s[q * 2 + 1] += bf2f((unsigned short)(vv[q] >> 16));
        }
    }
    float4 o0, o1;
    o0.x = s[0]; o0.y = s[1]; o0.z = s[2]; o0.w = s[3];
    o1.x = s[4]; o1.y = s[5]; o1.z = s[6]; o1.w = s[7];
    float* dst = outg + (size_t)blockIdx.y * 262144 + i;
    *(float4*)(dst) = o0;
    *(float4*)(dst + 4) = o1;
}

extern "C" void kernel_launch(void* const* d_in, const int* in_sizes, int n_in,
                              void* d_out, int out_size, void* d_ws, size_t ws_size,
                              hipStream_t stream) {
    const float* x   = (const float*)d_in[0];   // [4,1024,256]
    const float* phi = (const float*)d_in[1];   // [1024,24]
    const float* Mp  = (const float*)d_in[2];   // [24,256,256]
    const float* Mm  = (const float*)d_in[3];   // [24,256,256]
    float* out = (float*)d_out;                 // [4,1024,256]

    char* ws = (char*)d_ws;
    unsigned short* xb    = (unsigned short*)(ws);             //  2,097,152 B
    unsigned short* MbT   = (unsigned short*)(ws + 2097152);   //  6,291,456 B
    unsigned short* ToepA = (unsigned short*)(ws + 8388608);   // 12,582,912 B
    unsigned short* Zbuf  = (unsigned short*)(ws + 20971520);  // g * 25,165,824 B
    const size_t fixed = 20971520;

    int g = 4, kg = 16;
    auto need = [&](int gg, int kk) {
        return fixed + (size_t)gg * 25165824 + (size_t)gg * (size_t)kk * 524288;
    };
    if (need(4, 16) > ws_size) {
        kg = 12;
        if (need(4, 12) > ws_size) {
            g = 2; kg = 16;
            if (need(2, 16) > ws_size) {
                kg = 12;
                if (need(2, 12) > ws_size) {
                    g = 1; kg = 16;
                    if (need(1, 16) > ws_size) {
                        kg = 12;
                        if (need(1, 12) > ws_size) kg = 6;
                    }
                }
            }
        }
    }
    unsigned short* partial = (unsigned short*)(ws + fixed + (size_t)g * 25165824);

    k_prep_all<<<dim3(4864), dim3(256), 0, stream>>>(x, phi, Mp, Mm, xb, ToepA, MbT);

    for (int b0 = 0; b0 < 4; b0 += g) {
        k_stage1<<<dim3(8, 96, g), dim3(256), 0, stream>>>(xb + (size_t)b0 * 262144, MbT, Zbuf);
        k_stage2<<<dim3(4, 2 * g, kg), dim3(256), 0, stream>>>(Zbuf, ToepA, partial, 48 / kg);
        k_reduce<<<dim3(128, g), dim3(256), 0, stream>>>(partial, out + (size_t)b0 * 262144, kg);
    }
}